// Round 1
// 319.053 us; speedup vs baseline: 1.0195x; 1.0195x over previous
//
#include <hip/hip_runtime.h>
#include <hip/hip_bf16.h>
#include <stdint.h>

#define B_ 8
#define L_ 2048
#define D_ 256

typedef unsigned short u16;
typedef __attribute__((ext_vector_type(4))) float f32x4;
typedef __attribute__((ext_vector_type(8))) short bf16x8;
typedef __attribute__((ext_vector_type(4))) short s16x4;

__device__ __forceinline__ u16 f2b(float f) {
  union { float f; unsigned u; } v; v.f = f;
  unsigned r = v.u + 0x7FFFu + ((v.u >> 16) & 1u);
  return (u16)(r >> 16);
}

__device__ __forceinline__ float b2f(u16 h) {
  union { unsigned u; float f; } v; v.u = (unsigned)h << 16; return v.f;
}

__device__ __forceinline__ void comb(float& m, float& s, float m2, float s2) {
  float mn = fmaxf(m, m2);
  s = s * __expf(m - mn) + s2 * __expf(m2 - mn);
  m = mn;
}

__device__ __forceinline__ void async_copy16(const void* g, u16* l) {
  __builtin_amdgcn_global_load_lds(
      (const __attribute__((address_space(1))) unsigned*)g,
      (__attribute__((address_space(3))) unsigned*)l,
      16, 0, 0);
}

// ---- shared GEMM core: C[128x128] tile, A[M,K]·B[N,K]^T, K contiguous ----
template<int KD>
__device__ __forceinline__ void gemm_core(const u16* __restrict__ Ag,
                                          const u16* __restrict__ Bg,
                                          int tile_m, int tile_n,
                                          u16* lds_a, u16* lds_b,
                                          f32x4 acc[4][4]) {
  const int tid  = threadIdx.x;
  const int wave = tid >> 6, lane = tid & 63;
  const int qd = lane >> 4, ln = lane & 15;
  const int wm = wave >> 1, wn = wave & 1;
  const int lrow = lane >> 2;         // 0..15
  const int lcol = (lane & 3) * 8;    // element offset (16B chunks)
  const u16* Abase = Ag + (size_t)tile_m * KD + lcol;
  const u16* Bbase = Bg + (size_t)tile_n * KD + lcol;

  for (int k0 = 0; k0 < KD; k0 += 32) {
#pragma unroll
    for (int j = 0; j < 2; ++j) {
      const int r0 = j * 64 + wave * 16;   // wave-uniform
      async_copy16(Abase + (size_t)(r0 + lrow) * KD + k0, lds_a + r0 * 32);
      async_copy16(Bbase + (size_t)(r0 + lrow) * KD + k0, lds_b + r0 * 32);
    }
    __syncthreads();
    bf16x8 af[4], bg[4];
#pragma unroll
    for (int i = 0; i < 4; ++i) {
      af[i] = *(const bf16x8*)(lds_a + (wm * 64 + i * 16 + ln) * 32 + qd * 8);
      bg[i] = *(const bf16x8*)(lds_b + (wn * 64 + i * 16 + ln) * 32 + qd * 8);
    }
#pragma unroll
    for (int i = 0; i < 4; ++i)
#pragma unroll
      for (int j = 0; j < 4; ++j)
        acc[i][j] = __builtin_amdgcn_mfma_f32_16x16x32_bf16(af[i], bg[j], acc[i][j], 0, 0, 0);
    __syncthreads();
  }
}

// ---- 1. convert x and W to bf16 ----
__global__ __launch_bounds__(256) void cvt_kernel(const float* __restrict__ x,
    const float* __restrict__ Wq, const float* __restrict__ Wk, const float* __restrict__ Wv,
    u16* __restrict__ xb, u16* __restrict__ Wb) {
  const int i = blockIdx.x * 256 + threadIdx.x;  // float4 index
  const int NX4 = (B_ * L_ * D_) / 4;            // 1,048,576
  f32x4 v;
  u16* dst;
  if (i < NX4) {
    v = ((const f32x4*)x)[i];
    dst = xb + (size_t)i * 4;
  } else {
    int wi = i - NX4;                 // 0..49151
    int z = wi >> 14;                 // which W (16384 f4 each)
    int off = wi & 16383;
    const float* W = (z == 0) ? Wq : (z == 1 ? Wk : Wv);
    v = ((const f32x4*)W)[off];
    dst = Wb + (size_t)z * 65536 + (size_t)off * 4;
  }
  unsigned p0 = (unsigned)f2b(v.x) | ((unsigned)f2b(v.y) << 16);
  unsigned p1 = (unsigned)f2b(v.z) | ((unsigned)f2b(v.w) << 16);
  *(uint2*)dst = make_uint2(p0, p1);
}

// ---- 2. QKV projection: y = x @ W^T + b ----
__global__ __launch_bounds__(256) void qkv_gemm(const u16* __restrict__ xb, const u16* __restrict__ Wb,
    const float* __restrict__ bq, const float* __restrict__ bk, const float* __restrict__ bv,
    u16* __restrict__ Qb, u16* __restrict__ Kb, u16* __restrict__ Vb,
    float* __restrict__ out_sp) {
  __shared__ u16 lds_a[128 * 32], lds_b[128 * 32];
  const int z = blockIdx.z;
  const float* bias = (z == 0) ? bq : (z == 1 ? bk : bv);
  u16* dst = (z == 0) ? Qb : (z == 1 ? Kb : Vb);
  const int tile_m = blockIdx.x * 128, tile_n = blockIdx.y * 128;
  f32x4 acc[4][4];
#pragma unroll
  for (int i = 0; i < 4; ++i)
#pragma unroll
    for (int j = 0; j < 4; ++j) acc[i][j] = (f32x4){0.f, 0.f, 0.f, 0.f};
  gemm_core<256>(xb, Wb + (size_t)z * 256 * 256, tile_m, tile_n, lds_a, lds_b, acc);

  const int lane = threadIdx.x & 63, wave = threadIdx.x >> 6;
  const int qd = lane >> 4, ln = lane & 15, wm = wave >> 1, wn = wave & 1;
#pragma unroll
  for (int i = 0; i < 4; ++i)
#pragma unroll
    for (int j = 0; j < 4; ++j) {
      const int col = tile_n + wn * 64 + j * 16 + ln;
      const float bvv = bias[col];
      const int row0 = tile_m + wm * 64 + i * 16 + qd * 4;
#pragma unroll
      for (int r = 0; r < 4; ++r) {
        const int row = row0 + r;
        const float val = acc[i][j][r] + bvv;
        dst[(size_t)row * D_ + col] = f2b(val);
        if (z == 0) {
          const int bb = row >> 11, l = row & 2047;
          out_sp[((size_t)bb * (2 * L_) + l) * D_ + col] = val;
        }
      }
    }
}

// ---- 3. transpose V (per batch [L,D] -> [D,L]) ----
__global__ __launch_bounds__(256) void transpose_v(const u16* __restrict__ Vb, u16* __restrict__ Vbt) {
  const int b = blockIdx.z;
  const int l0 = blockIdx.x * 64;
  const int d0 = blockIdx.y * 64;
  __shared__ u16 t[64][65];
  const int tx = threadIdx.x & 63;
  const int ty = threadIdx.x >> 6;
  const u16* src = Vb + (size_t)b * L_ * D_;
  for (int j = ty; j < 64; j += 4)
    t[j][tx] = src[(size_t)(l0 + j) * D_ + d0 + tx];
  __syncthreads();
  u16* dst = Vbt + (size_t)b * D_ * L_;
  for (int j = ty; j < 64; j += 4)
    dst[(size_t)(d0 + j) * L_ + l0 + tx] = t[tx][j];
}

// ---- 4. E = Q K^T / 16 -> bf16 workspace, fused per-tile column-softmax partials ----
// partial layout: pm/ps[tile_mi(16)][b(8)][col(2048)]
__global__ __launch_bounds__(256) void e_gemm(const u16* __restrict__ Qb, const u16* __restrict__ Kb,
                                              u16* __restrict__ Eb16,
                                              float* __restrict__ pm, float* __restrict__ ps) {
  __shared__ u16 lds_a[128 * 32], lds_b[128 * 32];
  __shared__ float sm_m[4][64], sm_s[4][64];
  const int b = blockIdx.z;
  const int tile_m = blockIdx.x * 128, tile_n = blockIdx.y * 128;
  f32x4 acc[4][4];
#pragma unroll
  for (int i = 0; i < 4; ++i)
#pragma unroll
    for (int j = 0; j < 4; ++j) acc[i][j] = (f32x4){0.f, 0.f, 0.f, 0.f};
  gemm_core<256>(Qb + (size_t)b * L_ * D_, Kb + (size_t)b * L_ * D_, tile_m, tile_n, lds_a, lds_b, acc);

  u16* Eb = Eb16 + (size_t)b * L_ * L_;
  const int tid = threadIdx.x;
  const int lane = tid & 63, wave = tid >> 6;
  const int qd = lane >> 4, ln = lane & 15, wm = wave >> 1, wn = wave & 1;
#pragma unroll
  for (int j = 0; j < 4; ++j) {
    const int col = tile_n + wn * 64 + j * 16 + ln;
    const int row0 = tile_m + wm * 64 + qd * 4;
    float m = -1e30f;
#pragma unroll
    for (int i = 0; i < 4; ++i)
#pragma unroll
      for (int r = 0; r < 4; ++r)
        m = fmaxf(m, acc[i][j][r] * 0.0625f);
    float s = 0.f;
#pragma unroll
    for (int i = 0; i < 4; ++i)
#pragma unroll
      for (int r = 0; r < 4; ++r) {
        const float e = acc[i][j][r] * 0.0625f;
        Eb[(size_t)(row0 + i * 16 + r) * L_ + col] = f2b(e);
        s += __expf(e - m);
      }
    comb(m, s, __shfl_xor(m, 16), __shfl_xor(s, 16));
    comb(m, s, __shfl_xor(m, 32), __shfl_xor(s, 32));
    if (qd == 0) { sm_m[wave][j * 16 + ln] = m; sm_s[wave][j * 16 + ln] = s; }
  }
  __syncthreads();
  if (tid < 128) {
    const int w = tid >> 6, c = tid & 63;   // w = wn, columns wn*64 + c
    float m = sm_m[w][c], s = sm_s[w][c];
    comb(m, s, sm_m[w + 2][c], sm_s[w + 2][c]);
    const size_t idx = (size_t)blockIdx.x * (B_ * L_) + (size_t)b * L_ + tile_n + w * 64 + c;
    pm[idx] = m;
    ps[idx] = s;
  }
}

// ---- 5. reduce 16 tile partials -> m, r=1/s per (b,col) ----
__global__ __launch_bounds__(256) void stats_reduce(const float* __restrict__ pm,
                                                    const float* __restrict__ ps,
                                                    float* __restrict__ mOut, float* __restrict__ rOut) {
  const int idx = blockIdx.x * 256 + threadIdx.x;  // 0..16383 = b*2048+col
  float m = -1e30f, s = 0.f;
#pragma unroll
  for (int t = 0; t < 16; ++t)
    comb(m, s, pm[t * (B_ * L_) + idx], ps[t * (B_ * L_) + idx]);
  mOut[idx] = m;
  rOut[idx] = 1.0f / s;
}

// ---- 6. fused softmax-apply + C = A V ----
// Each block: 32 q-rows × all 256 d-cols, K=2048. Reads Eb bf16, computes
// A = exp(e-m[k])*r[k] once per element, writes A f32 (output) + bf16 to LDS,
// MFMAs against async-staged V^T slice. Grid (64,8) = 512 blocks = 2/CU.
__global__ __launch_bounds__(256) void av_fused(const u16* __restrict__ Eb16, const u16* __restrict__ Vbt,
                                                const float* __restrict__ mArr, const float* __restrict__ rArr,
                                                float* __restrict__ Aout, float* __restrict__ out_sp) {
  __shared__ u16 lds_b[256 * 32];   // V^T slice [d=256][k=32]
  __shared__ u16 lds_a[32 * 32];    // A slice  [q=32][k=32]
  const int b = blockIdx.y;
  const int tile_m = blockIdx.x * 32;
  const int tid = threadIdx.x;
  const int wave = tid >> 6, lane = tid & 63;
  const int qd = lane >> 4, ln = lane & 15;
  const int lrow = lane >> 2, lcol = (lane & 3) * 8;

  const u16* Vb_ = Vbt + (size_t)b * D_ * L_ + lcol;
  // A-staging: thread t handles row tid>>3 (0..31), k-offset (tid&7)*4
  const int arow = tid >> 3, koff = (tid & 7) * 4;
  const u16* Erow = Eb16 + ((size_t)b * L_ + tile_m + arow) * L_ + koff;
  float* Arow = Aout + ((size_t)(b * L_ + tile_m + arow)) * L_ + koff;
  const float* mrow = mArr + (size_t)b * L_ + koff;
  const float* rrow = rArr + (size_t)b * L_ + koff;

  f32x4 acc[2][4];
#pragma unroll
  for (int i = 0; i < 2; ++i)
#pragma unroll
    for (int j = 0; j < 4; ++j) acc[i][j] = (f32x4){0.f, 0.f, 0.f, 0.f};

  for (int k0 = 0; k0 < L_; k0 += 32) {
    // stage V^T slice: rows r0..r0+15 per issue, 4 issues/wave covers 256 rows
#pragma unroll
    for (int jj = 0; jj < 4; ++jj) {
      const int r0 = wave * 64 + jj * 16;
      async_copy16(Vb_ + (size_t)(r0 + lrow) * L_ + k0, lds_b + r0 * 32);
    }
    // stage A slice with softmax apply (each element touched exactly once)
    s16x4 ev = *(const s16x4*)(Erow + k0);
    const f32x4 mv = *(const f32x4*)(mrow + k0);
    const f32x4 rv = *(const f32x4*)(rrow + k0);
    f32x4 a;
    a.x = __expf(b2f((u16)ev.x) - mv.x) * rv.x;
    a.y = __expf(b2f((u16)ev.y) - mv.y) * rv.y;
    a.z = __expf(b2f((u16)ev.z) - mv.z) * rv.z;
    a.w = __expf(b2f((u16)ev.w) - mv.w) * rv.w;
    *(f32x4*)(Arow + k0) = a;                          // A output (f32)
    uint2 pk;
    pk.x = (unsigned)f2b(a.x) | ((unsigned)f2b(a.y) << 16);
    pk.y = (unsigned)f2b(a.z) | ((unsigned)f2b(a.w) << 16);
    *(uint2*)(lds_a + (size_t)tid * 4) = pk;           // linear: row*64B + koff*2B
    __syncthreads();

    bf16x8 af[2], bg[4];
#pragma unroll
    for (int i = 0; i < 2; ++i)
      af[i] = *(const bf16x8*)(lds_a + (i * 16 + ln) * 32 + qd * 8);
#pragma unroll
    for (int j = 0; j < 4; ++j)
      bg[j] = *(const bf16x8*)(lds_b + (wave * 64 + j * 16 + ln) * 32 + qd * 8);
#pragma unroll
    for (int i = 0; i < 2; ++i)
#pragma unroll
      for (int j = 0; j < 4; ++j)
        acc[i][j] = __builtin_amdgcn_mfma_f32_16x16x32_bf16(af[i], bg[j], acc[i][j], 0, 0, 0);
    __syncthreads();
  }

  // epilogue: C tile -> S_p rows [L_, 2L_)
#pragma unroll
  for (int i = 0; i < 2; ++i)
#pragma unroll
    for (int j = 0; j < 4; ++j) {
      const int col = wave * 64 + j * 16 + ln;
      const int row0 = tile_m + i * 16 + qd * 4;
#pragma unroll
      for (int r = 0; r < 4; ++r)
        out_sp[((size_t)b * (2 * L_) + L_ + row0 + r) * D_ + col] = acc[i][j][r];
    }
}

extern "C" void kernel_launch(void* const* d_in, const int* in_sizes, int n_in,
                              void* d_out, int out_size, void* d_ws, size_t ws_size,
                              hipStream_t stream) {
  const float* x  = (const float*)d_in[0];
  const float* Wq = (const float*)d_in[1];
  const float* bq = (const float*)d_in[2];
  const float* Wk = (const float*)d_in[3];
  const float* bk = (const float*)d_in[4];
  const float* Wv = (const float*)d_in[5];
  const float* bv = (const float*)d_in[6];

  float* out    = (float*)d_out;                      // S_p: 8*4096*256 floats
  float* outA   = out + (size_t)B_ * (2 * L_) * D_;   // A region: 8*2048*2048 floats

  // workspace layout (u16 elements)
  u16* w    = (u16*)d_ws;
  u16* xb   = w;                    // 4,194,304
  u16* Wb   = xb + 4194304;         //   196,608
  u16* Qb   = Wb + 196608;          // 4,194,304
  u16* Kb   = Qb + 4194304;         // 4,194,304
  u16* Vb   = Kb + 4194304;         // 4,194,304
  u16* Vbt  = Vb + 4194304;         // 4,194,304
  u16* Eb16 = Vbt + 4194304;        // 33,554,432 (E in bf16)
  float* mArr = (float*)(Eb16 + 33554432);  // 16384
  float* rArr = mArr + B_ * L_;             // 16384
  float* pm   = rArr + B_ * L_;             // 262144
  float* ps   = pm + 16 * B_ * L_;          // 262144

  cvt_kernel<<<4288, 256, 0, stream>>>(x, Wq, Wk, Wv, xb, Wb);
  qkv_gemm<<<dim3(128, 2, 3), 256, 0, stream>>>(xb, Wb, bq, bk, bv, Qb, Kb, Vb, out);
  transpose_v<<<dim3(32, 4, 8), 256, 0, stream>>>(Vb, Vbt);
  e_gemm<<<dim3(16, 16, 8), 256, 0, stream>>>(Qb, Kb, Eb16, pm, ps);
  stats_reduce<<<64, 256, 0, stream>>>(pm, ps, mArr, rArr);
  av_fused<<<dim3(64, 8), 256, 0, stream>>>(Eb16, Vbt, mArr, rArr, outA, out);
}

// Round 2
// 296.770 us; speedup vs baseline: 1.0961x; 1.0751x over previous
//
#include <hip/hip_runtime.h>
#include <hip/hip_bf16.h>
#include <stdint.h>

#define B_ 8
#define L_ 2048
#define D_ 256

typedef unsigned short u16;
typedef __attribute__((ext_vector_type(4))) float f32x4;
typedef __attribute__((ext_vector_type(8))) short bf16x8;

__device__ __forceinline__ u16 f2b(float f) {
  union { float f; unsigned u; } v; v.f = f;
  unsigned r = v.u + 0x7FFFu + ((v.u >> 16) & 1u);
  return (u16)(r >> 16);
}

__device__ __forceinline__ float b2f(u16 h) {
  union { unsigned u; float f; } v; v.u = (unsigned)h << 16; return v.f;
}

__device__ __forceinline__ void comb(float& m, float& s, float m2, float s2) {
  float mn = fmaxf(m, m2);
  s = s * __expf(m - mn) + s2 * __expf(m2 - mn);
  m = mn;
}

__device__ __forceinline__ void async_copy16(const void* g, u16* l) {
  __builtin_amdgcn_global_load_lds(
      (const __attribute__((address_space(1))) unsigned*)g,
      (__attribute__((address_space(3))) unsigned*)l,
      16, 0, 0);
}

// ---- shared GEMM core: C[128x128] tile, A[M,K]·B[N,K]^T, K contiguous ----
template<int KD>
__device__ __forceinline__ void gemm_core(const u16* __restrict__ Ag,
                                          const u16* __restrict__ Bg,
                                          int tile_m, int tile_n,
                                          u16* lds_a, u16* lds_b,
                                          f32x4 acc[4][4]) {
  const int tid  = threadIdx.x;
  const int wave = tid >> 6, lane = tid & 63;
  const int qd = lane >> 4, ln = lane & 15;
  const int wm = wave >> 1, wn = wave & 1;
  const int lrow = lane >> 2;         // 0..15
  const int lcol = (lane & 3) * 8;    // element offset (16B chunks)
  const u16* Abase = Ag + (size_t)tile_m * KD + lcol;
  const u16* Bbase = Bg + (size_t)tile_n * KD + lcol;

  for (int k0 = 0; k0 < KD; k0 += 32) {
#pragma unroll
    for (int j = 0; j < 2; ++j) {
      const int r0 = j * 64 + wave * 16;   // wave-uniform
      async_copy16(Abase + (size_t)(r0 + lrow) * KD + k0, lds_a + r0 * 32);
      async_copy16(Bbase + (size_t)(r0 + lrow) * KD + k0, lds_b + r0 * 32);
    }
    __syncthreads();
    bf16x8 af[4], bg[4];
#pragma unroll
    for (int i = 0; i < 4; ++i) {
      af[i] = *(const bf16x8*)(lds_a + (wm * 64 + i * 16 + ln) * 32 + qd * 8);
      bg[i] = *(const bf16x8*)(lds_b + (wn * 64 + i * 16 + ln) * 32 + qd * 8);
    }
#pragma unroll
    for (int i = 0; i < 4; ++i)
#pragma unroll
      for (int j = 0; j < 4; ++j)
        acc[i][j] = __builtin_amdgcn_mfma_f32_16x16x32_bf16(af[i], bg[j], acc[i][j], 0, 0, 0);
    __syncthreads();
  }
}

// ---- 1. convert x and W to bf16 ----
__global__ __launch_bounds__(256) void cvt_kernel(const float* __restrict__ x,
    const float* __restrict__ Wq, const float* __restrict__ Wk, const float* __restrict__ Wv,
    u16* __restrict__ xb, u16* __restrict__ Wb) {
  const int i = blockIdx.x * 256 + threadIdx.x;  // float4 index
  const int NX4 = (B_ * L_ * D_) / 4;            // 1,048,576
  f32x4 v;
  u16* dst;
  if (i < NX4) {
    v = ((const f32x4*)x)[i];
    dst = xb + (size_t)i * 4;
  } else {
    int wi = i - NX4;                 // 0..49151
    int z = wi >> 14;                 // which W (16384 f4 each)
    int off = wi & 16383;
    const float* W = (z == 0) ? Wq : (z == 1 ? Wk : Wv);
    v = ((const f32x4*)W)[off];
    dst = Wb + (size_t)z * 65536 + (size_t)off * 4;
  }
  unsigned p0 = (unsigned)f2b(v.x) | ((unsigned)f2b(v.y) << 16);
  unsigned p1 = (unsigned)f2b(v.z) | ((unsigned)f2b(v.w) << 16);
  *(uint2*)dst = make_uint2(p0, p1);
}

// ---- 2. QKV projection: y = x @ W^T + b.  z==2 writes V^T directly. ----
__global__ __launch_bounds__(256) void qkv_gemm(const u16* __restrict__ xb, const u16* __restrict__ Wb,
    const float* __restrict__ bq, const float* __restrict__ bk, const float* __restrict__ bv,
    u16* __restrict__ Qb, u16* __restrict__ Kb, u16* __restrict__ Vbt,
    float* __restrict__ out_sp) {
  __shared__ u16 lds[8192];   // gemm staging 2x4096, reused by epilogue (64x128)
  const int z = blockIdx.z;
  const float* bias = (z == 0) ? bq : (z == 1 ? bk : bv);
  const int tile_m = blockIdx.x * 128, tile_n = blockIdx.y * 128;
  f32x4 acc[4][4];
#pragma unroll
  for (int i = 0; i < 4; ++i)
#pragma unroll
    for (int j = 0; j < 4; ++j) acc[i][j] = (f32x4){0.f, 0.f, 0.f, 0.f};
  gemm_core<256>(xb, Wb + (size_t)z * 256 * 256, tile_m, tile_n, lds, lds + 4096, acc);

  const int tid = threadIdx.x, lane = tid & 63, wave = tid >> 6;
  const int qd = lane >> 4, ln = lane & 15, wm = wave >> 1, wn = wave & 1;

  if (z < 2) {
    u16* dst = (z == 0) ? Qb : Kb;
#pragma unroll
    for (int p = 0; p < 2; ++p) {
      __syncthreads();
      if (wm == p) {
#pragma unroll
        for (int i = 0; i < 4; ++i)
#pragma unroll
          for (int j = 0; j < 4; ++j) {
            const int col = wn * 64 + j * 16 + ln;
            const float bvv = bias[tile_n + col];
#pragma unroll
            for (int r = 0; r < 4; ++r) {
              const int row = i * 16 + qd * 4 + r;      // 0..63 within pass
              const float val = acc[i][j][r] + bvv;
              lds[row * 128 + col] = f2b(val);
              if (z == 0) {
                const int grow = tile_m + p * 64 + row;
                const int bb = grow >> 11, l = grow & 2047;
                out_sp[((size_t)bb * (2 * L_) + l) * D_ + tile_n + col] = val;
              }
            }
          }
      }
      __syncthreads();
      // coalesced store: 64 rows x 128 cols bf16
      const int r = tid >> 2;
#pragma unroll
      for (int s = 0; s < 4; ++s) {
        const int chunk = (tid & 3) + s * 4;            // 0..15
        bf16x8 v = *(const bf16x8*)(lds + r * 128 + chunk * 8);
        *(bf16x8*)(dst + (size_t)(tile_m + p * 64 + r) * D_ + tile_n + chunk * 8) = v;
      }
    }
  } else {
    // z==2: store V^T. Pass p covers d-cols [tile_n+p*64, +64); LDS = [d_local 64][l_local 128]
    const int bb = tile_m >> 11, l0 = tile_m & 2047;
    u16* dstb = Vbt + (size_t)bb * D_ * L_;
#pragma unroll
    for (int p = 0; p < 2; ++p) {
      __syncthreads();
      if (wn == p) {
#pragma unroll
        for (int i = 0; i < 4; ++i)
#pragma unroll
          for (int j = 0; j < 4; ++j) {
            const int col = j * 16 + ln;                // d_local 0..63
            const float bvv = bias[tile_n + p * 64 + col];
#pragma unroll
            for (int r = 0; r < 4; ++r) {
              const int row = wm * 64 + i * 16 + qd * 4 + r;  // l_local 0..127
              lds[col * 128 + row] = f2b(acc[i][j][r] + bvv);
            }
          }
      }
      __syncthreads();
      const int dr = tid >> 2;
#pragma unroll
      for (int s = 0; s < 4; ++s) {
        const int chunk = (tid & 3) + s * 4;
        bf16x8 v = *(const bf16x8*)(lds + dr * 128 + chunk * 8);
        *(bf16x8*)(dstb + (size_t)(tile_n + p * 64 + dr) * L_ + l0 + chunk * 8) = v;
      }
    }
  }
}

// ---- 3. E = Q K^T / 16 -> bf16 workspace (coalesced), fused column-softmax partials ----
__global__ __launch_bounds__(256) void e_gemm(const u16* __restrict__ Qb, const u16* __restrict__ Kb,
                                              u16* __restrict__ Eb16,
                                              float* __restrict__ pm, float* __restrict__ ps) {
  __shared__ u16 lds[8192];
  __shared__ float sm_m[4][64], sm_s[4][64];
  const int b = blockIdx.z;
  const int tile_m = blockIdx.x * 128, tile_n = blockIdx.y * 128;
  f32x4 acc[4][4];
#pragma unroll
  for (int i = 0; i < 4; ++i)
#pragma unroll
    for (int j = 0; j < 4; ++j) acc[i][j] = (f32x4){0.f, 0.f, 0.f, 0.f};
  gemm_core<256>(Qb + (size_t)b * L_ * D_, Kb + (size_t)b * L_ * D_, tile_m, tile_n, lds, lds + 4096, acc);

  u16* Eb = Eb16 + (size_t)b * L_ * L_;
  const int tid = threadIdx.x;
  const int lane = tid & 63, wave = tid >> 6;
  const int qd = lane >> 4, ln = lane & 15, wm = wave >> 1, wn = wave & 1;

  // per-column (softmax over q) partials
#pragma unroll
  for (int j = 0; j < 4; ++j) {
    float m = -1e30f;
#pragma unroll
    for (int i = 0; i < 4; ++i)
#pragma unroll
      for (int r = 0; r < 4; ++r)
        m = fmaxf(m, acc[i][j][r] * 0.0625f);
    float s = 0.f;
#pragma unroll
    for (int i = 0; i < 4; ++i)
#pragma unroll
      for (int r = 0; r < 4; ++r)
        s += __expf(acc[i][j][r] * 0.0625f - m);
    comb(m, s, __shfl_xor(m, 16), __shfl_xor(s, 16));
    comb(m, s, __shfl_xor(m, 32), __shfl_xor(s, 32));
    if (qd == 0) { sm_m[wave][j * 16 + ln] = m; sm_s[wave][j * 16 + ln] = s; }
  }
  __syncthreads();
  if (tid < 128) {
    const int w = tid >> 6, c = tid & 63;   // w = wn, columns wn*64 + c
    float m = sm_m[w][c], s = sm_s[w][c];
    comb(m, s, sm_m[w + 2][c], sm_s[w + 2][c]);
    const size_t idx = (size_t)blockIdx.x * (B_ * L_) + (size_t)b * L_ + tile_n + w * 64 + c;
    pm[idx] = m;
    ps[idx] = s;
  }

  // E store via LDS transpose: pass p covers rows [tile_m+p*64, +64)
#pragma unroll
  for (int p = 0; p < 2; ++p) {
    __syncthreads();
    if (wm == p) {
#pragma unroll
      for (int i = 0; i < 4; ++i)
#pragma unroll
        for (int j = 0; j < 4; ++j) {
          const int col = wn * 64 + j * 16 + ln;
#pragma unroll
          for (int r = 0; r < 4; ++r) {
            const int row = i * 16 + qd * 4 + r;
            lds[row * 128 + col] = f2b(acc[i][j][r] * 0.0625f);
          }
        }
    }
    __syncthreads();
    const int r = tid >> 2;
#pragma unroll
    for (int s = 0; s < 4; ++s) {
      const int chunk = (tid & 3) + s * 4;
      bf16x8 v = *(const bf16x8*)(lds + r * 128 + chunk * 8);
      *(bf16x8*)(Eb + (size_t)(tile_m + p * 64 + r) * L_ + tile_n + chunk * 8) = v;
    }
  }
}

// ---- 4. reduce 16 tile partials -> m, r=1/s per (b,col) ----
__global__ __launch_bounds__(256) void stats_reduce(const float* __restrict__ pm,
                                                    const float* __restrict__ ps,
                                                    float* __restrict__ mOut, float* __restrict__ rOut) {
  const int idx = blockIdx.x * 256 + threadIdx.x;  // 0..16383 = b*2048+col
  float m = -1e30f, s = 0.f;
#pragma unroll
  for (int t = 0; t < 16; ++t)
    comb(m, s, pm[t * (B_ * L_) + idx], ps[t * (B_ * L_) + idx]);
  mOut[idx] = m;
  rOut[idx] = 1.0f / s;
}

// ---- 5. fused softmax-apply + C = A V, K-step 64 with E/m/r prefetch ----
__global__ __launch_bounds__(256) void av_fused(const u16* __restrict__ Eb16, const u16* __restrict__ Vbt,
                                                const float* __restrict__ mArr, const float* __restrict__ rArr,
                                                float* __restrict__ Aout, float* __restrict__ out_sp) {
  __shared__ u16 lds_b[256 * 64];   // V^T slice [d=256][k=64]  32 KB
  __shared__ u16 lds_a[32 * 64];    // A slice  [q=32][k=64]    4 KB
  const int b = blockIdx.y;
  const int tile_m = blockIdx.x * 32;
  const int tid = threadIdx.x;
  const int wave = tid >> 6, lane = tid & 63;
  const int qd = lane >> 4, ln = lane & 15;
  const int lrow = lane >> 3, lcol = (lane & 7) * 8;

  const u16* Vb_ = Vbt + (size_t)b * D_ * L_ + lcol;
  // A-staging: thread t handles row tid>>3 (0..31), k-offset (tid&7)*8
  const int arow = tid >> 3, koff = (tid & 7) * 8;
  const u16* Erow = Eb16 + ((size_t)b * L_ + tile_m + arow) * L_ + koff;
  float* Arow = Aout + ((size_t)b * L_ + tile_m + arow) * L_ + koff;
  const float* mrow = mArr + (size_t)b * L_ + koff;
  const float* rrow = rArr + (size_t)b * L_ + koff;

  f32x4 acc[2][4];
#pragma unroll
  for (int i = 0; i < 2; ++i)
#pragma unroll
    for (int j = 0; j < 4; ++j) acc[i][j] = (f32x4){0.f, 0.f, 0.f, 0.f};

  bf16x8 ev = *(const bf16x8*)(Erow);
  f32x4 mv0 = *(const f32x4*)(mrow),     mv1 = *(const f32x4*)(mrow + 4);
  f32x4 rv0 = *(const f32x4*)(rrow),     rv1 = *(const f32x4*)(rrow + 4);

  for (int k0 = 0; k0 < L_; k0 += 64) {
    // 1. issue V^T staging (8 issues/wave, 8 rows each)
#pragma unroll
    for (int jj = 0; jj < 8; ++jj) {
      const int r0 = wave * 64 + jj * 8;
      async_copy16(Vb_ + (size_t)(r0 + lrow) * L_ + k0, lds_b + r0 * 64);
    }
    // 2. softmax-apply current E regs; write A f32; pack bf16 -> LDS
    float a0 = __expf(b2f((u16)ev[0]) - mv0.x) * rv0.x;
    float a1 = __expf(b2f((u16)ev[1]) - mv0.y) * rv0.y;
    float a2 = __expf(b2f((u16)ev[2]) - mv0.z) * rv0.z;
    float a3 = __expf(b2f((u16)ev[3]) - mv0.w) * rv0.w;
    float a4 = __expf(b2f((u16)ev[4]) - mv1.x) * rv1.x;
    float a5 = __expf(b2f((u16)ev[5]) - mv1.y) * rv1.y;
    float a6 = __expf(b2f((u16)ev[6]) - mv1.z) * rv1.z;
    float a7 = __expf(b2f((u16)ev[7]) - mv1.w) * rv1.w;
    *(f32x4*)(Arow + k0)     = (f32x4){a0, a1, a2, a3};
    *(f32x4*)(Arow + k0 + 4) = (f32x4){a4, a5, a6, a7};
    uint4 pk;
    pk.x = (unsigned)f2b(a0) | ((unsigned)f2b(a1) << 16);
    pk.y = (unsigned)f2b(a2) | ((unsigned)f2b(a3) << 16);
    pk.z = (unsigned)f2b(a4) | ((unsigned)f2b(a5) << 16);
    pk.w = (unsigned)f2b(a6) | ((unsigned)f2b(a7) << 16);
    *(uint4*)(lds_a + (size_t)tid * 8) = pk;     // linear [arow][64]
    // 3. prefetch next k-slice E/m/r (latency rides the V drain at the barrier)
    const int kn = (k0 + 64) & (L_ - 1);
    ev  = *(const bf16x8*)(Erow + kn);
    mv0 = *(const f32x4*)(mrow + kn); mv1 = *(const f32x4*)(mrow + kn + 4);
    rv0 = *(const f32x4*)(rrow + kn); rv1 = *(const f32x4*)(rrow + kn + 4);
    __syncthreads();
    // 4. fragments + MFMA (2 k-substeps of 32)
    bf16x8 af[2][2], bg[4][2];
#pragma unroll
    for (int i = 0; i < 2; ++i)
#pragma unroll
      for (int ks = 0; ks < 2; ++ks)
        af[i][ks] = *(const bf16x8*)(lds_a + (i * 16 + ln) * 64 + ks * 32 + qd * 8);
#pragma unroll
    for (int j = 0; j < 4; ++j)
#pragma unroll
      for (int ks = 0; ks < 2; ++ks)
        bg[j][ks] = *(const bf16x8*)(lds_b + (wave * 64 + j * 16 + ln) * 64 + ks * 32 + qd * 8);
#pragma unroll
    for (int ks = 0; ks < 2; ++ks)
#pragma unroll
      for (int i = 0; i < 2; ++i)
#pragma unroll
        for (int j = 0; j < 4; ++j)
          acc[i][j] = __builtin_amdgcn_mfma_f32_16x16x32_bf16(af[i][ks], bg[j][ks], acc[i][j], 0, 0, 0);
    __syncthreads();
  }

  // epilogue: C tile -> S_p rows [L_, 2L_)
#pragma unroll
  for (int i = 0; i < 2; ++i)
#pragma unroll
    for (int j = 0; j < 4; ++j) {
      const int col = wave * 64 + j * 16 + ln;
      const int row0 = tile_m + i * 16 + qd * 4;
#pragma unroll
      for (int r = 0; r < 4; ++r)
        out_sp[((size_t)b * (2 * L_) + L_ + row0 + r) * D_ + col] = acc[i][j][r];
    }
}

extern "C" void kernel_launch(void* const* d_in, const int* in_sizes, int n_in,
                              void* d_out, int out_size, void* d_ws, size_t ws_size,
                              hipStream_t stream) {
  const float* x  = (const float*)d_in[0];
  const float* Wq = (const float*)d_in[1];
  const float* bq = (const float*)d_in[2];
  const float* Wk = (const float*)d_in[3];
  const float* bk = (const float*)d_in[4];
  const float* Wv = (const float*)d_in[5];
  const float* bv = (const float*)d_in[6];

  float* out    = (float*)d_out;                      // S_p: 8*4096*256 floats
  float* outA   = out + (size_t)B_ * (2 * L_) * D_;   // A region: 8*2048*2048 floats

  // workspace layout (u16 elements)
  u16* w    = (u16*)d_ws;
  u16* xb   = w;                    // 4,194,304
  u16* Wb   = xb + 4194304;         //   196,608
  u16* Qb   = Wb + 196608;          // 4,194,304
  u16* Kb   = Qb + 4194304;         // 4,194,304
  u16* Vbt  = Kb + 4194304;         // 4,194,304 (V^T, written directly by qkv_gemm)
  u16* Eb16 = Vbt + 4194304;        // 33,554,432 (E in bf16)
  float* mArr = (float*)(Eb16 + 33554432);  // 16384
  float* rArr = mArr + B_ * L_;             // 16384
  float* pm   = rArr + B_ * L_;             // 262144
  float* ps   = pm + 16 * B_ * L_;          // 262144

  cvt_kernel<<<4288, 256, 0, stream>>>(x, Wq, Wk, Wv, xb, Wb);
  qkv_gemm<<<dim3(128, 2, 3), 256, 0, stream>>>(xb, Wb, bq, bk, bv, Qb, Kb, Vbt, out);
  e_gemm<<<dim3(16, 16, 8), 256, 0, stream>>>(Qb, Kb, Eb16, pm, ps);
  stats_reduce<<<64, 256, 0, stream>>>(pm, ps, mArr, rArr);
  av_fused<<<dim3(64, 8), 256, 0, stream>>>(Eb16, Vbt, mArr, rArr, outA, out);
}